// Round 21
// baseline (572.268 us; speedup 1.0000x reference)
//
#include <hip/hip_runtime.h>
#include <hip/hip_bf16.h>

#define CDIM 384
#define NQKV 1152
#define HEADS 12
#define SHIFT_ 4
#define SCALE_Q 0.17677669529663687f  // 32^-0.5

typedef __attribute__((ext_vector_type(8))) short bf16x8;
typedef __attribute__((ext_vector_type(4))) float f32x4;
typedef __attribute__((ext_vector_type(4))) float float4_t;
typedef __attribute__((ext_vector_type(4))) unsigned u32x4;
typedef __attribute__((ext_vector_type(2))) unsigned u32x2;

__device__ inline short f2bf(float f) {
    union { float f; unsigned u; } v; v.f = f;
    unsigned r = v.u + 0x7FFFu + ((v.u >> 16) & 1u);
    return (short)(r >> 16);
}

__device__ inline unsigned cvtpk(float lo, float hi) {
    unsigned r;
    asm("v_cvt_pk_bf16_f32 %0, %1, %2" : "=v"(r) : "v"(lo), "v"(hi));
    return r;
}

__device__ inline bf16x8 mk8(unsigned w0, unsigned w1, unsigned w2, unsigned w3) {
    u32x4 t = {w0, w1, w2, w3};
    return __builtin_bit_cast(bf16x8, t);
}

__device__ inline bf16x8 pack8(float4_t a, float4_t b) {
    return mk8(cvtpk(a[0], a[1]), cvtpk(a[2], a[3]),
               cvtpk(b[0], b[1]), cvtpk(b[2], b[3]));
}

// Regroup: two acc tiles -> MFMA operand fragment.  [R9-verified]
__device__ inline bf16x8 regroup(unsigned p0, unsigned p1, unsigned p2,
                                 unsigned p3, int lane) {
    int lhi = (lane >> 4) & 3;
    int s0 = (lane & 15) + ((lhi & 1) ? 32 : 0);
    int s1 = s0 + 16;
    unsigned a0 = __shfl(p0, s0), b0 = __shfl(p2, s0);
    unsigned a1 = __shfl(p1, s0), b1 = __shfl(p3, s0);
    unsigned a2 = __shfl(p0, s1), b2 = __shfl(p2, s1);
    unsigned a3 = __shfl(p1, s1), b3 = __shfl(p3, s1);
    bool hi = lhi >= 2;
    return mk8(hi ? b0 : a0, hi ? b1 : a1, hi ? b2 : a2, hi ? b3 : a3);
}

__device__ inline void gl16(const short* g, const short* l) {
    __builtin_amdgcn_global_load_lds((const __attribute__((address_space(1))) void*)g,
                                     (__attribute__((address_space(3))) void*)l, 16, 0, 0);
}

__device__ inline int invswz(int c) {
    int b2 = (c >> 2) & 1, b3 = (c >> 3) & 1, b4 = (c >> 4) & 1;
    return (c & ~7) | ((b2 ^ b4) << 2) | (((((c >> 1) & 1)) ^ b3) << 1) | ((c & 1) ^ b2 ^ b4);
}

__device__ inline int region_id(int wIdx, int tok) {
    int gh = ((wIdx >> 3) << 3) + (tok >> 3);
    int gw = (wIdx & 7) * 8 + (tok & 7);
    int rh = gh < 56 ? 0 : (gh < 60 ? 1 : 2);
    int rw = gw < 56 ? 0 : (gw < 60 ? 1 : 2);
    return rh * 3 + rw;
}

// Cst row offset: +8 shorts every 8 rows (conflict-free transpose reads)
__device__ inline int crow(int row) { return row * 136 + (row >> 3) * 8; }

// shifted-window source row base (in floats) for window-space row mg
__device__ inline size_t xrow(int mg) {
    int tok = mg & 63, win = mg >> 6;
    int b = win >> 6, wIdx = win & 63;
    int gh = ((wIdx >> 3) << 3) + (tok >> 3);
    int gw = (wIdx & 7) * 8 + (tok & 7);
    int sh_ = (gh + SHIFT_) & 63, sw_ = (gw + SHIFT_) & 63;
    return (size_t)(b * 4096 + sh_ * 64 + sw_) * CDIM;
}

// ---------------- prep: weight transpose->bf16, bias in acc layout ---------
__global__ void prep_kernel(const float* __restrict__ qkv_w,
                            const float* __restrict__ proj_w,
                            const float* __restrict__ bias_table,
                            const int* __restrict__ rel_index,
                            short* __restrict__ qkvwt,
                            short* __restrict__ projwt,
                            float* __restrict__ biasP) {
    int t = blockIdx.x * 256 + threadIdx.x;
    if (t < NQKV * CDIM) {             // qkvwt[n][k] = qkv_w[k][n]
        int n = t / CDIM, k = t - n * CDIM;
        qkvwt[t] = f2bf(qkv_w[k * NQKV + n]);
    }
    if (t < CDIM * CDIM) {             // projwt[n][k] = proj_w[k][n]
        int n = t / CDIM, k = t - n * CDIM;
        projwt[t] = f2bf(proj_w[k * CDIM + n]);
    }
    if (t < HEADS * 16 * 64 * 4) {     // biasP[h][kt*4+qt][lane][r]
        int r = t & 3, lane = (t >> 2) & 63, g = (t >> 8) & 15, h = t >> 12;
        int kt = g >> 2, qt = g & 3;
        int key = kt * 16 + (lane >> 4) * 4 + r;
        int query = qt * 16 + (lane & 15);
        biasP[t] = bias_table[rel_index[query * 64 + key] * HEADS + h];
    }
}

// ---------------- GEMM1: fused shift+cvt, counted-vmcnt pipeline (R16) -----
// 128x128 tile, BK=32. A double-buffered (reg-staged fp32->bf16), B
// TRIPLE-buffered via gl16 issued 2 steps ahead.  Raw s_barrier with
// s_waitcnt vmcnt(6) lgkmcnt(0).  LDS 40960B -> 4 blocks/CU.
// Outputs stored WITHOUT nt hint so L3 retains them for attn_reg.
__global__ __launch_bounds__(256) void gemm_qkv(
    const float* __restrict__ x, const short* __restrict__ wt,
    const float* __restrict__ qkv_b, short* __restrict__ qkbuf,
    short* __restrict__ vT)
{
    __shared__ alignas(16) char smemb[40960];
    short* As = (short*)smemb;                       // 2 x 4096 shorts
    short* Bs = As + 8192;                           // 3 x 4096 shorts
    short* Cst = (short*)smemb;                      // overlay, 17520 shorts
    int tid = threadIdx.x;
    int hw = blockIdx.x;                             // 9216 = 8*1152
    int lb = (hw & 7) * 1152 + (hw >> 3);
    int bm = lb / 9, bn = lb - bm * 9;
    int m0 = bm * 128, n0 = bn * 128;

    int lane = tid & 63, wv = tid >> 6;
    int c0 = wv * 128 + lane, c1 = c0 + 64;          // chunks 0..511
    const float* Asrc0 = x + xrow(m0 + (c0 >> 2)) + (c0 & 3) * 8;
    const float* Asrc1 = x + xrow(m0 + (c1 >> 2)) + (c1 & 3) * 8;
    short* Aw0 = As + (c0 ^ ((c0 >> 2) & 7)) * 8;
    short* Aw1 = As + (c1 ^ ((c1 >> 2) & 7)) * 8;
    int l0 = invswz(c0), l1 = invswz(c1);
    const short* Bg0 = wt + (size_t)(n0 + (l0 >> 2)) * CDIM + (l0 & 3) * 8;
    const short* Bg1 = wt + (size_t)(n0 + (l1 >> 2)) * CDIM + (l1 & 3) * 8;
    short* Bdst0 = Bs + wv * 1024;
    short* Bdst1 = Bdst0 + 512;

    int wr = wv >> 1, wc = wv & 1;
    int lrow = lane & 15, lhi = lane >> 4;
    int arow = wr * 64 + lrow, brow = wc * 64 + lrow;
    const short* ard = As + ((((arow * 64 + lhi * 16)) ^ ((lrow & 7) << 4)) >> 1);
    const short* brd = Bs + ((((brow * 64 + lhi * 16)) ^ ((lrow & 7) << 4)) >> 1);

    f32x4 zero = {0.f, 0.f, 0.f, 0.f};
    f32x4 acc[4][4];
    #pragma unroll
    for (int i = 0; i < 4; i++)
        #pragma unroll
        for (int j = 0; j < 4; j++) acc[i][j] = zero;

    // A prefetch register sets: set (k&1) holds A(k); loaded at step k-2.
    float4_t sA0[4], sA1[4];
    {
        sA0[0] = __builtin_nontemporal_load((const float4_t*)(Asrc0));
        sA0[1] = __builtin_nontemporal_load((const float4_t*)(Asrc0 + 4));
        sA0[2] = __builtin_nontemporal_load((const float4_t*)(Asrc1));
        sA0[3] = __builtin_nontemporal_load((const float4_t*)(Asrc1 + 4));
        gl16(Bg0, Bdst0);
        gl16(Bg1, Bdst1);
        gl16(Bg0 + 32, Bdst0 + 4096);
        gl16(Bg1 + 32, Bdst1 + 4096);
        *(bf16x8*)Aw0 = pack8(sA0[0], sA0[1]);
        *(bf16x8*)Aw1 = pack8(sA0[2], sA0[3]);
        sA1[0] = __builtin_nontemporal_load((const float4_t*)(Asrc0 + 32));
        sA1[1] = __builtin_nontemporal_load((const float4_t*)(Asrc0 + 36));
        sA1[2] = __builtin_nontemporal_load((const float4_t*)(Asrc1 + 32));
        sA1[3] = __builtin_nontemporal_load((const float4_t*)(Asrc1 + 36));
    }
    __builtin_amdgcn_sched_barrier(0);
    asm volatile("s_waitcnt vmcnt(6) lgkmcnt(0)");
    __builtin_amdgcn_s_barrier();
    __builtin_amdgcn_sched_barrier(0);

    #pragma unroll
    for (int ks = 0; ks < 12; ks++) {
        int curA = (ks & 1) * 4096, nxtA = 4096 - curA;
        int curB = (ks % 3) * 4096;
        // issue B(ks+2) gl16 into buf (ks+2)%3
        if (ks < 10) {
            int k2 = (ks + 2) * 32;
            int b2 = ((ks + 2) % 3) * 4096;
            gl16(Bg0 + k2, Bdst0 + b2);
            gl16(Bg1 + k2, Bdst1 + b2);
        }
        // write A(ks+1) into nxtA (regs landed; set (ks+1)&1)
        if (ks < 11) {
            if ((ks + 1) & 1) {
                *(bf16x8*)(Aw0 + nxtA) = pack8(sA1[0], sA1[1]);
                *(bf16x8*)(Aw1 + nxtA) = pack8(sA1[2], sA1[3]);
            } else {
                *(bf16x8*)(Aw0 + nxtA) = pack8(sA0[0], sA0[1]);
                *(bf16x8*)(Aw1 + nxtA) = pack8(sA0[2], sA0[3]);
            }
        }
        // issue A(ks+2) loads into set ks&1
        if (ks < 10) {
            int k2 = (ks + 2) * 32;
            if (ks & 1) {
                sA1[0] = __builtin_nontemporal_load((const float4_t*)(Asrc0 + k2));
                sA1[1] = __builtin_nontemporal_load((const float4_t*)(Asrc0 + k2 + 4));
                sA1[2] = __builtin_nontemporal_load((const float4_t*)(Asrc1 + k2));
                sA1[3] = __builtin_nontemporal_load((const float4_t*)(Asrc1 + k2 + 4));
            } else {
                sA0[0] = __builtin_nontemporal_load((const float4_t*)(Asrc0 + k2));
                sA0[1] = __builtin_nontemporal_load((const float4_t*)(Asrc0 + k2 + 4));
                sA0[2] = __builtin_nontemporal_load((const float4_t*)(Asrc1 + k2));
                sA0[3] = __builtin_nontemporal_load((const float4_t*)(Asrc1 + k2 + 4));
            }
        }
        // compute on current buffers
        bf16x8 af[4], bfr[4];
        #pragma unroll
        for (int t = 0; t < 4; t++) af[t]  = *(const bf16x8*)(ard + curA + t * 512);
        #pragma unroll
        for (int t = 0; t < 4; t++) bfr[t] = *(const bf16x8*)(brd + curB + t * 512);
        __builtin_amdgcn_s_setprio(1);
        #pragma unroll
        for (int i = 0; i < 4; i++)
            #pragma unroll
            for (int j = 0; j < 4; j++)
                acc[i][j] = __builtin_amdgcn_mfma_f32_16x16x32_bf16(af[i], bfr[j], acc[i][j], 0, 0, 0);
        __builtin_amdgcn_s_setprio(0);
        // counted-drain barrier: keep the 6 newest loads in flight
        __builtin_amdgcn_sched_barrier(0);
        asm volatile("s_waitcnt vmcnt(6) lgkmcnt(0)");
        __builtin_amdgcn_s_barrier();
        __builtin_amdgcn_sched_barrier(0);
    }
    // ---- epilogue: +bias (+q scale) -> padded Cst -> layout stores ----
    #pragma unroll
    for (int tj = 0; tj < 4; tj++) {
        int col = wc * 64 + tj * 16 + lrow;
        int cg = n0 + col;
        float bias = qkv_b[cg];
        float sc = (cg < CDIM) ? SCALE_Q : 1.0f;
        #pragma unroll
        for (int ti = 0; ti < 4; ti++) {
            int row0 = wr * 64 + ti * 16 + lhi * 4;
            #pragma unroll
            for (int r = 0; r < 4; r++)
                Cst[crow(row0 + r) + col] = f2bf((acc[ti][tj][r] + bias) * sc);
        }
    }
    __syncthreads();
    if (bn < 6) {
        // Q/K: row-major b128 stores (cacheable -> L3 retains for attn)
        #pragma unroll
        for (int i = 0; i < 8; i++) {
            int rr = i * 16 + (tid >> 4);
            int cc = (tid & 15) * 8;
            bf16x8 v = *(const bf16x8*)(Cst + crow(rr) + cc);
            *(bf16x8*)(qkbuf + (size_t)(m0 + rr) * 768 + n0 + cc) = v;
        }
    } else {
        // V: transpose to vT[win][head][dim][token] (cacheable)
        #pragma unroll
        for (int it = 0; it < 8; it++) {
            int t = it * 256 + tid;            // 2048 tasks
            int col = t >> 4, tk8 = t & 15;    // col 0..127, 8-token chunk
            bf16x8 v;
            #pragma unroll
            for (int j = 0; j < 8; j++)
                v[j] = Cst[crow(tk8 * 8 + j) + col];
            int win = bm * 2 + (tk8 >> 3);
            int head = (bn - 6) * 4 + (col >> 5);
            int dim = col & 31;
            *(bf16x8*)(vT + (((size_t)win * HEADS + head) * 32 + dim) * 64 + (tk8 & 7) * 8) = v;
        }
    }
}

// ---------------- attn: zero-LDS/barrier; ONE WAVE = (window, head) --------
__global__ __launch_bounds__(256) void attn_reg(
    const short* __restrict__ qkbuf, const short* __restrict__ vT,
    const float* __restrict__ biasP, short* __restrict__ attno)
{
    int tid = threadIdx.x;
    int lane = tid & 63, wv = tid >> 6;
    int lrow = lane & 15, lhi = lane >> 4;
    int task = blockIdx.x * 4 + wv;            // 24576 = 2048 win x 12 heads
    int w = task / 12, h = task - w * 12;
    int wIdx = w & 63;
    bool needmask = ((wIdx >> 3) == 7) || ((wIdx & 7) == 7);

    int rq[4], rk[4][4];
    #pragma unroll
    for (int qt = 0; qt < 4; qt++) rq[qt] = region_id(wIdx, qt * 16 + lrow);
    #pragma unroll
    for (int kt = 0; kt < 4; kt++)
        #pragma unroll
        for (int r = 0; r < 4; r++)
            rk[kt][r] = region_id(wIdx, kt * 16 + lhi * 4 + r);

    f32x4 zero = {0.f, 0.f, 0.f, 0.f};
    const short* qbase = qkbuf + (size_t)(w * 64) * 768;

    // K fragments: A-op, lane holds K[key=kt*16+lrow][d=lhi*8+e]
    bf16x8 kf[4];
    #pragma unroll
    for (int kt = 0; kt < 4; kt++)
        kf[kt] = *(const bf16x8*)(qbase + (size_t)(kt * 16 + lrow) * 768 + CDIM + h * 32 + lhi * 8);
    // per-qt: S^T column block -> softmax -> P fragments
    bf16x8 pa[4][2];
    #pragma unroll
    for (int qt = 0; qt < 4; qt++) {
        bf16x8 qf = *(const bf16x8*)(qbase + (size_t)(qt * 16 + lrow) * 768 + h * 32 + lhi * 8);
        f32x4 st[4];
        __builtin_amdgcn_s_setprio(1);
        #pragma unroll
        for (int kt = 0; kt < 4; kt++)
            st[kt] = __builtin_amdgcn_mfma_f32_16x16x32_bf16(kf[kt], qf, zero, 0, 0, 0);
        __builtin_amdgcn_s_setprio(0);
        float pv[16]; float sum = 0.f;
        #pragma unroll
        for (int kt = 0; kt < 4; kt++) {
            f32x4 bb = *(const f32x4*)(biasP + (((size_t)h * 16 + kt * 4 + qt) * 64 + lane) * 4);
            #pragma unroll
            for (int r = 0; r < 4; r++) {
                float p = __expf(st[kt][r] + bb[r]);
                p = (needmask && (rq[qt] != rk[kt][r])) ? 0.f : p;
                pv[kt * 4 + r] = p; sum += p;
            }
        }
        sum += __shfl_xor(sum, 16);
        sum += __shfl_xor(sum, 32);
        float rcp = 1.0f / sum;
        unsigned a0 = cvtpk(pv[0] * rcp, pv[1] * rcp);
        unsigned a1 = cvtpk(pv[2] * rcp, pv[3] * rcp);
        unsigned a2 = cvtpk(pv[4] * rcp, pv[5] * rcp);
        unsigned a3 = cvtpk(pv[6] * rcp, pv[7] * rcp);
        pa[qt][0] = regroup(a0, a1, a2, a3, lane);
        a0 = cvtpk(pv[8] * rcp,  pv[9] * rcp);
        a1 = cvtpk(pv[10] * rcp, pv[11] * rcp);
        a2 = cvtpk(pv[12] * rcp, pv[13] * rcp);
        a3 = cvtpk(pv[14] * rcp, pv[15] * rcp);
        pa[qt][1] = regroup(a0, a1, a2, a3, lane);
    }
    // V fragments from vT: A-op
    const short* vb = vT + ((size_t)w * HEADS + h) * 32 * 64;
    bf16x8 vfrag[2][2];
    #pragma unroll
    for (int ks2 = 0; ks2 < 2; ks2++)
        #pragma unroll
        for (int dt = 0; dt < 2; dt++)
            vfrag[ks2][dt] = *(const bf16x8*)(vb + (size_t)(dt * 16 + lrow) * 64 + ks2 * 32 + lhi * 8);
    // PV^T: ao2[qt][dt], col=query(lane&15), rows=4 consecutive dims
    f32x4 ao2[4][2];
    #pragma unroll
    for (int qt = 0; qt < 4; qt++) { ao2[qt][0] = zero; ao2[qt][1] = zero; }
    __builtin_amdgcn_s_setprio(1);
    #pragma unroll
    for (int ks2 = 0; ks2 < 2; ks2++)
        #pragma unroll
        for (int qt = 0; qt < 4; qt++) {
            ao2[qt][0] = __builtin_amdgcn_mfma_f32_16x16x32_bf16(vfrag[ks2][0], pa[qt][ks2], ao2[qt][0], 0, 0, 0);
            ao2[qt][1] = __builtin_amdgcn_mfma_f32_16x16x32_bf16(vfrag[ks2][1], pa[qt][ks2], ao2[qt][1], 0, 0, 0);
        }
    __builtin_amdgcn_s_setprio(0);
    // paired 8B stores (cacheable -> L3 retains for gemm_proj)
    short* abase = attno + (size_t)(w * 64) * CDIM + h * 32 + lhi * 4;
    #pragma unroll
    for (int qt = 0; qt < 4; qt++) {
        int token = qt * 16 + lrow;
        short* p0 = abase + (size_t)token * CDIM;
        u32x2 s0, s1;
        s0[0] = cvtpk(ao2[qt][0][0], ao2[qt][0][1]);
        s0[1] = cvtpk(ao2[qt][0][2], ao2[qt][0][3]);
        s1[0] = cvtpk(ao2[qt][1][0], ao2[qt][1][1]);
        s1[1] = cvtpk(ao2[qt][1][2], ao2[qt][1][3]);
        *(u32x2*)(p0) = s0;
        *(u32x2*)(p0 + 16) = s1;
    }
}

// ---------------- GEMM2 (pipelined): out = attno @ proj_w^T + b ------------
__global__ __launch_bounds__(256) void gemm_proj(
    const short* __restrict__ a, const short* __restrict__ wt,
    const float* __restrict__ proj_b, float* __restrict__ out)
{
    __shared__ alignas(16) short As[8192];     // 2 buffers
    __shared__ alignas(16) short Bs[8192];
    int tid = threadIdx.x;
    int hw = blockIdx.x;                       // 3072 blocks, %8==0
    int lb = (hw & 7) * 384 + (hw >> 3);
    int bm = lb / 3, bn = lb - bm * 3;
    int m0 = bm * 128, n0 = bn * 128;

    int lane = tid & 63, wv = tid >> 6;
    int c0 = wv * 128 + lane, c1 = c0 + 64;
    int l0 = invswz(c0), l1 = invswz(c1);
    const short* Ag0 = a + (size_t)(m0 + (l0 >> 2)) * CDIM + (l0 & 3) * 8;
    const short* Ag1 = a + (size_t)(m0 + (l1 >> 2)) * CDIM + (l1 & 3) * 8;
    const short* Bg0 = wt + (size_t)(n0 + (l0 >> 2)) * CDIM + (l0 & 3) * 8;
    const short* Bg1 = wt + (size_t)(n0 + (l1 >> 2)) * CDIM + (l1 & 3) * 8;
    short* Adst0 = As + wv * 1024;
    short* Adst1 = Adst0 + 512;
    short* Bdst0 = Bs + wv * 1024;
    short* Bdst1 = Bdst0 + 512;

    int wr = wv >> 1, wc = wv & 1;
    int lrow = lane & 15, lhi = lane >> 4;
    int arow = wr * 64 + lrow, brow = wc * 64 + lrow;
    const short* ard = As + ((((arow * 64 + lhi * 16)) ^ ((lrow & 7) << 4)) >> 1);
    const short* brd = Bs + ((((brow * 64 + lhi * 16)) ^ ((lrow & 7) << 4)) >> 1);

    f32x4 zero = {0.f, 0.f, 0.f, 0.f};
    f32x4 acc[4][4];
    #pragma unroll
    for (int i = 0; i < 4; i++)
        #pragma unroll
        for (int j = 0; j < 4; j++) acc[i][j] = zero;

    gl16(Ag0, Adst0);
    gl16(Bg0, Bdst0);
    gl16(Ag1, Adst1);
    gl16(Bg1, Bdst1);
    __syncthreads();

    #pragma unroll
    for (int ks = 0; ks < 12; ks++) {
        int cur = (ks & 1) * 4096, nxt = 4096 - cur;
        if (ks < 11) {
            int k1 = (ks + 1) * 32;
            gl16(Ag0 + k1, Adst0 + nxt);
            gl16(Bg0 + k1, Bdst0 + nxt);
            gl16(Ag1 + k1, Adst1 + nxt);
            gl16(Bg1 + k1, Bdst1 + nxt);
        }
        bf16x8 af[4], bfr[4];
        #pragma unroll
        for (int t = 0; t < 4; t++) af[t]  = *(const bf16x8*)(ard + cur + t * 512);
        #pragma unroll
        for (int t = 0; t < 4; t++) bfr[t] = *(const bf16x8*)(brd + cur + t * 512);
        __builtin_amdgcn_s_setprio(1);
        #pragma unroll
        for (int i = 0; i < 4; i++)
            #pragma unroll
            for (int j = 0; j < 4; j++)
                acc[i][j] = __builtin_amdgcn_mfma_f32_16x16x32_bf16(af[i], bfr[j], acc[i][j], 0, 0, 0);
        __builtin_amdgcn_s_setprio(0);
        __syncthreads();
    }
    // epilogue: window reverse + unshift, fp32 NT out (never re-read)
    #pragma unroll
    for (int ti = 0; ti < 4; ti++) {
        #pragma unroll
        for (int r = 0; r < 4; r++) {
            int m = m0 + wr * 64 + ti * 16 + lhi * 4 + r;
            int b = m >> 12, wIdx = (m >> 6) & 63, tok = m & 63;
            int gh = ((wIdx >> 3) << 3) + (tok >> 3);
            int gw = (wIdx & 7) * 8 + (tok & 7);
            int ih = (gh + SHIFT_) & 63, iw = (gw + SHIFT_) & 63;
            size_t ob = ((size_t)(b << 12) + ih * 64 + iw) * CDIM;
            #pragma unroll
            for (int tj = 0; tj < 4; tj++) {
                int col = n0 + wc * 64 + tj * 16 + lrow;
                float v = acc[ti][tj][r] + proj_b[col];
                __builtin_nontemporal_store(v, &out[ob + col]);
            }
        }
    }
}

extern "C" void kernel_launch(void* const* d_in, const int* in_sizes, int n_in,
                              void* d_out, int out_size, void* d_ws, size_t ws_size,
                              hipStream_t stream) {
    const float* x          = (const float*)d_in[0];
    const float* qkv_w      = (const float*)d_in[1];
    const float* qkv_b      = (const float*)d_in[2];
    const float* proj_w     = (const float*)d_in[3];
    const float* proj_b     = (const float*)d_in[4];
    const float* bias_table = (const float*)d_in[5];
    const int*   rel_index  = (const int*)d_in[6];
    float* out = (float*)d_out;
    char* ws = (char*)d_ws;

    short* qkvwt = (short*)(ws);                    //    884736 B
    short* projwt = (short*)(ws + 884736);          //    294912 B
    float* biasP  = (float*)(ws + 1179648);         //    196608 B
    short* qkbuf  = (short*)(ws + 1376256);         // 201326592 B
    short* vT     = (short*)(ws + 202702848);       // 100663296 B
    short* attno  = (short*)(ws + 303366144);       // 100663296 B -> ~404 MB

    prep_kernel<<<1728, 256, 0, stream>>>(qkv_w, proj_w, bias_table, rel_index,
                                          qkvwt, projwt, biasP);
    gemm_qkv<<<9216, 256, 0, stream>>>(x, qkvwt, qkv_b, qkbuf, vT);
    attn_reg<<<6144, 256, 0, stream>>>(qkbuf, vT, biasP, attno);
    gemm_proj<<<3072, 256, 0, stream>>>(attno, projwt, proj_b, out);
}

// Round 22
// 408.537 us; speedup vs baseline: 1.4008x; 1.4008x over previous
//
#include <hip/hip_runtime.h>
#include <hip/hip_bf16.h>

#define CDIM 384
#define NQKV 1152
#define HEADS 12
#define SHIFT_ 4
#define SCALE_Q 0.17677669529663687f  // 32^-0.5

typedef __attribute__((ext_vector_type(8))) short bf16x8;
typedef __attribute__((ext_vector_type(4))) float f32x4;
typedef __attribute__((ext_vector_type(4))) float float4_t;
typedef __attribute__((ext_vector_type(4))) unsigned u32x4;
typedef __attribute__((ext_vector_type(2))) unsigned u32x2;

__device__ inline short f2bf(float f) {
    union { float f; unsigned u; } v; v.f = f;
    unsigned r = v.u + 0x7FFFu + ((v.u >> 16) & 1u);
    return (short)(r >> 16);
}

__device__ inline unsigned cvtpk(float lo, float hi) {
    unsigned r;
    asm("v_cvt_pk_bf16_f32 %0, %1, %2" : "=v"(r) : "v"(lo), "v"(hi));
    return r;
}

__device__ inline bf16x8 mk8(unsigned w0, unsigned w1, unsigned w2, unsigned w3) {
    u32x4 t = {w0, w1, w2, w3};
    return __builtin_bit_cast(bf16x8, t);
}

__device__ inline bf16x8 pack8(float4_t a, float4_t b) {
    return mk8(cvtpk(a[0], a[1]), cvtpk(a[2], a[3]),
               cvtpk(b[0], b[1]), cvtpk(b[2], b[3]));
}

// Regroup: two acc tiles -> MFMA operand fragment.  [R9-verified]
__device__ inline bf16x8 regroup(unsigned p0, unsigned p1, unsigned p2,
                                 unsigned p3, int lane) {
    int lhi = (lane >> 4) & 3;
    int s0 = (lane & 15) + ((lhi & 1) ? 32 : 0);
    int s1 = s0 + 16;
    unsigned a0 = __shfl(p0, s0), b0 = __shfl(p2, s0);
    unsigned a1 = __shfl(p1, s0), b1 = __shfl(p3, s0);
    unsigned a2 = __shfl(p0, s1), b2 = __shfl(p2, s1);
    unsigned a3 = __shfl(p1, s1), b3 = __shfl(p3, s1);
    bool hi = lhi >= 2;
    return mk8(hi ? b0 : a0, hi ? b1 : a1, hi ? b2 : a2, hi ? b3 : a3);
}

__device__ inline void gl16(const short* g, const short* l) {
    __builtin_amdgcn_global_load_lds((const __attribute__((address_space(1))) void*)g,
                                     (__attribute__((address_space(3))) void*)l, 16, 0, 0);
}

__device__ inline int invswz(int c) {
    int b2 = (c >> 2) & 1, b3 = (c >> 3) & 1, b4 = (c >> 4) & 1;
    return (c & ~7) | ((b2 ^ b4) << 2) | (((((c >> 1) & 1)) ^ b3) << 1) | ((c & 1) ^ b2 ^ b4);
}

__device__ inline int region_id(int wIdx, int tok) {
    int gh = ((wIdx >> 3) << 3) + (tok >> 3);
    int gw = (wIdx & 7) * 8 + (tok & 7);
    int rh = gh < 56 ? 0 : (gh < 60 ? 1 : 2);
    int rw = gw < 56 ? 0 : (gw < 60 ? 1 : 2);
    return rh * 3 + rw;
}

// Cst row offset: +8 shorts every 8 rows (conflict-free transpose reads)
__device__ inline int crow(int row) { return row * 136 + (row >> 3) * 8; }

// shifted-window source row base (in floats) for window-space row mg
__device__ inline size_t xrow(int mg) {
    int tok = mg & 63, win = mg >> 6;
    int b = win >> 6, wIdx = win & 63;
    int gh = ((wIdx >> 3) << 3) + (tok >> 3);
    int gw = (wIdx & 7) * 8 + (tok & 7);
    int sh_ = (gh + SHIFT_) & 63, sw_ = (gw + SHIFT_) & 63;
    return (size_t)(b * 4096 + sh_ * 64 + sw_) * CDIM;
}

// ---------------- prep: weight transpose->bf16, bias in acc layout ---------
__global__ void prep_kernel(const float* __restrict__ qkv_w,
                            const float* __restrict__ proj_w,
                            const float* __restrict__ bias_table,
                            const int* __restrict__ rel_index,
                            short* __restrict__ qkvwt,
                            short* __restrict__ projwt,
                            float* __restrict__ biasP) {
    int t = blockIdx.x * 256 + threadIdx.x;
    if (t < NQKV * CDIM) {             // qkvwt[n][k] = qkv_w[k][n]
        int n = t / CDIM, k = t - n * CDIM;
        qkvwt[t] = f2bf(qkv_w[k * NQKV + n]);
    }
    if (t < CDIM * CDIM) {             // projwt[n][k] = proj_w[k][n]
        int n = t / CDIM, k = t - n * CDIM;
        projwt[t] = f2bf(proj_w[k * CDIM + n]);
    }
    if (t < HEADS * 16 * 64 * 4) {     // biasP[h][kt*4+qt][lane][r]
        int r = t & 3, lane = (t >> 2) & 63, g = (t >> 8) & 15, h = t >> 12;
        int kt = g >> 2, qt = g & 3;
        int key = kt * 16 + (lane >> 4) * 4 + r;
        int query = qt * 16 + (lane & 15);
        biasP[t] = bias_table[rel_index[query * 64 + key] * HEADS + h];
    }
}

// ---------------- GEMM1: fused shift+cvt, counted-vmcnt pipeline (R16) -----
// 128x128 tile, BK=32. A double-buffered (reg-staged fp32->bf16), B
// TRIPLE-buffered via gl16 issued 2 steps ahead.  Raw s_barrier with
// s_waitcnt vmcnt(6) lgkmcnt(0).  LDS 40960B -> 4 blocks/CU.  [R16-verified]
__global__ __launch_bounds__(256) void gemm_qkv(
    const float* __restrict__ x, const short* __restrict__ wt,
    const float* __restrict__ qkv_b, short* __restrict__ qkbuf,
    short* __restrict__ vT)
{
    __shared__ alignas(16) char smemb[40960];
    short* As = (short*)smemb;                       // 2 x 4096 shorts
    short* Bs = As + 8192;                           // 3 x 4096 shorts
    short* Cst = (short*)smemb;                      // overlay, 17520 shorts
    int tid = threadIdx.x;
    int hw = blockIdx.x;                             // 9216 = 8*1152
    int lb = (hw & 7) * 1152 + (hw >> 3);
    int bm = lb / 9, bn = lb - bm * 9;
    int m0 = bm * 128, n0 = bn * 128;

    int lane = tid & 63, wv = tid >> 6;
    int c0 = wv * 128 + lane, c1 = c0 + 64;          // chunks 0..511
    const float* Asrc0 = x + xrow(m0 + (c0 >> 2)) + (c0 & 3) * 8;
    const float* Asrc1 = x + xrow(m0 + (c1 >> 2)) + (c1 & 3) * 8;
    short* Aw0 = As + (c0 ^ ((c0 >> 2) & 7)) * 8;
    short* Aw1 = As + (c1 ^ ((c1 >> 2) & 7)) * 8;
    int l0 = invswz(c0), l1 = invswz(c1);
    const short* Bg0 = wt + (size_t)(n0 + (l0 >> 2)) * CDIM + (l0 & 3) * 8;
    const short* Bg1 = wt + (size_t)(n0 + (l1 >> 2)) * CDIM + (l1 & 3) * 8;
    short* Bdst0 = Bs + wv * 1024;
    short* Bdst1 = Bdst0 + 512;

    int wr = wv >> 1, wc = wv & 1;
    int lrow = lane & 15, lhi = lane >> 4;
    int arow = wr * 64 + lrow, brow = wc * 64 + lrow;
    const short* ard = As + ((((arow * 64 + lhi * 16)) ^ ((lrow & 7) << 4)) >> 1);
    const short* brd = Bs + ((((brow * 64 + lhi * 16)) ^ ((lrow & 7) << 4)) >> 1);

    f32x4 zero = {0.f, 0.f, 0.f, 0.f};
    f32x4 acc[4][4];
    #pragma unroll
    for (int i = 0; i < 4; i++)
        #pragma unroll
        for (int j = 0; j < 4; j++) acc[i][j] = zero;

    // A prefetch register sets: set (k&1) holds A(k); loaded at step k-2.
    float4_t sA0[4], sA1[4];
    {
        sA0[0] = *(const float4_t*)(Asrc0);
        sA0[1] = *(const float4_t*)(Asrc0 + 4);
        sA0[2] = *(const float4_t*)(Asrc1);
        sA0[3] = *(const float4_t*)(Asrc1 + 4);
        gl16(Bg0, Bdst0);
        gl16(Bg1, Bdst1);
        gl16(Bg0 + 32, Bdst0 + 4096);
        gl16(Bg1 + 32, Bdst1 + 4096);
        *(bf16x8*)Aw0 = pack8(sA0[0], sA0[1]);
        *(bf16x8*)Aw1 = pack8(sA0[2], sA0[3]);
        sA1[0] = *(const float4_t*)(Asrc0 + 32);
        sA1[1] = *(const float4_t*)(Asrc0 + 36);
        sA1[2] = *(const float4_t*)(Asrc1 + 32);
        sA1[3] = *(const float4_t*)(Asrc1 + 36);
    }
    __builtin_amdgcn_sched_barrier(0);
    asm volatile("s_waitcnt vmcnt(6) lgkmcnt(0)");
    __builtin_amdgcn_s_barrier();
    __builtin_amdgcn_sched_barrier(0);

    #pragma unroll
    for (int ks = 0; ks < 12; ks++) {
        int curA = (ks & 1) * 4096, nxtA = 4096 - curA;
        int curB = (ks % 3) * 4096;
        // issue B(ks+2) gl16 into buf (ks+2)%3
        if (ks < 10) {
            int k2 = (ks + 2) * 32;
            int b2 = ((ks + 2) % 3) * 4096;
            gl16(Bg0 + k2, Bdst0 + b2);
            gl16(Bg1 + k2, Bdst1 + b2);
        }
        // write A(ks+1) into nxtA (regs landed; set (ks+1)&1)
        if (ks < 11) {
            if ((ks + 1) & 1) {
                *(bf16x8*)(Aw0 + nxtA) = pack8(sA1[0], sA1[1]);
                *(bf16x8*)(Aw1 + nxtA) = pack8(sA1[2], sA1[3]);
            } else {
                *(bf16x8*)(Aw0 + nxtA) = pack8(sA0[0], sA0[1]);
                *(bf16x8*)(Aw1 + nxtA) = pack8(sA0[2], sA0[3]);
            }
        }
        // issue A(ks+2) loads into set ks&1
        if (ks < 10) {
            int k2 = (ks + 2) * 32;
            if (ks & 1) {
                sA1[0] = *(const float4_t*)(Asrc0 + k2);
                sA1[1] = *(const float4_t*)(Asrc0 + k2 + 4);
                sA1[2] = *(const float4_t*)(Asrc1 + k2);
                sA1[3] = *(const float4_t*)(Asrc1 + k2 + 4);
            } else {
                sA0[0] = *(const float4_t*)(Asrc0 + k2);
                sA0[1] = *(const float4_t*)(Asrc0 + k2 + 4);
                sA0[2] = *(const float4_t*)(Asrc1 + k2);
                sA0[3] = *(const float4_t*)(Asrc1 + k2 + 4);
            }
        }
        // compute on current buffers
        bf16x8 af[4], bfr[4];
        #pragma unroll
        for (int t = 0; t < 4; t++) af[t]  = *(const bf16x8*)(ard + curA + t * 512);
        #pragma unroll
        for (int t = 0; t < 4; t++) bfr[t] = *(const bf16x8*)(brd + curB + t * 512);
        __builtin_amdgcn_s_setprio(1);
        #pragma unroll
        for (int i = 0; i < 4; i++)
            #pragma unroll
            for (int j = 0; j < 4; j++)
                acc[i][j] = __builtin_amdgcn_mfma_f32_16x16x32_bf16(af[i], bfr[j], acc[i][j], 0, 0, 0);
        __builtin_amdgcn_s_setprio(0);
        // counted-drain barrier: keep the 6 newest loads in flight
        __builtin_amdgcn_sched_barrier(0);
        asm volatile("s_waitcnt vmcnt(6) lgkmcnt(0)");
        __builtin_amdgcn_s_barrier();
        __builtin_amdgcn_sched_barrier(0);
    }
    // ---- epilogue: +bias (+q scale) -> padded Cst -> layout stores ----
    #pragma unroll
    for (int tj = 0; tj < 4; tj++) {
        int col = wc * 64 + tj * 16 + lrow;
        int cg = n0 + col;
        float bias = qkv_b[cg];
        float sc = (cg < CDIM) ? SCALE_Q : 1.0f;
        #pragma unroll
        for (int ti = 0; ti < 4; ti++) {
            int row0 = wr * 64 + ti * 16 + lhi * 4;
            #pragma unroll
            for (int r = 0; r < 4; r++)
                Cst[crow(row0 + r) + col] = f2bf((acc[ti][tj][r] + bias) * sc);
        }
    }
    __syncthreads();
    if (bn < 6) {
        // Q/K: row-major b128 NT stores, row stride 768
        #pragma unroll
        for (int i = 0; i < 8; i++) {
            int rr = i * 16 + (tid >> 4);
            int cc = (tid & 15) * 8;
            bf16x8 v = *(const bf16x8*)(Cst + crow(rr) + cc);
            __builtin_nontemporal_store(v,
                (bf16x8*)(qkbuf + (size_t)(m0 + rr) * 768 + n0 + cc));
        }
    } else {
        // V: transpose to vT[win][head][dim][token]
        #pragma unroll
        for (int it = 0; it < 8; it++) {
            int t = it * 256 + tid;            // 2048 tasks
            int col = t >> 4, tk8 = t & 15;    // col 0..127, 8-token chunk
            bf16x8 v;
            #pragma unroll
            for (int j = 0; j < 8; j++)
                v[j] = Cst[crow(tk8 * 8 + j) + col];
            int win = bm * 2 + (tk8 >> 3);
            int head = (bn - 6) * 4 + (col >> 5);
            int dim = col & 31;
            __builtin_nontemporal_store(v,
                (bf16x8*)(vT + (((size_t)win * HEADS + head) * 32 + dim) * 64 + (tk8 & 7) * 8));
        }
    }
}

// ---------------- attn: zero-LDS/barrier; ONE WAVE = (window, head) --------
__global__ __launch_bounds__(256) void attn_reg(
    const short* __restrict__ qkbuf, const short* __restrict__ vT,
    const float* __restrict__ biasP, short* __restrict__ attno)
{
    int tid = threadIdx.x;
    int lane = tid & 63, wv = tid >> 6;
    int lrow = lane & 15, lhi = lane >> 4;
    int task = blockIdx.x * 4 + wv;            // 24576 = 2048 win x 12 heads
    int w = task / 12, h = task - w * 12;
    int wIdx = w & 63;
    bool needmask = ((wIdx >> 3) == 7) || ((wIdx & 7) == 7);

    int rq[4], rk[4][4];
    #pragma unroll
    for (int qt = 0; qt < 4; qt++) rq[qt] = region_id(wIdx, qt * 16 + lrow);
    #pragma unroll
    for (int kt = 0; kt < 4; kt++)
        #pragma unroll
        for (int r = 0; r < 4; r++)
            rk[kt][r] = region_id(wIdx, kt * 16 + lhi * 4 + r);

    f32x4 zero = {0.f, 0.f, 0.f, 0.f};
    const short* qbase = qkbuf + (size_t)(w * 64) * 768;

    // K fragments: A-op, lane holds K[key=kt*16+lrow][d=lhi*8+e]
    bf16x8 kf[4];
    #pragma unroll
    for (int kt = 0; kt < 4; kt++)
        kf[kt] = __builtin_nontemporal_load(
            (const bf16x8*)(qbase + (size_t)(kt * 16 + lrow) * 768 + CDIM + h * 32 + lhi * 8));
    // per-qt: S^T column block -> softmax -> P fragments
    bf16x8 pa[4][2];
    #pragma unroll
    for (int qt = 0; qt < 4; qt++) {
        bf16x8 qf = __builtin_nontemporal_load(
            (const bf16x8*)(qbase + (size_t)(qt * 16 + lrow) * 768 + h * 32 + lhi * 8));
        f32x4 st[4];
        __builtin_amdgcn_s_setprio(1);
        #pragma unroll
        for (int kt = 0; kt < 4; kt++)
            st[kt] = __builtin_amdgcn_mfma_f32_16x16x32_bf16(kf[kt], qf, zero, 0, 0, 0);
        __builtin_amdgcn_s_setprio(0);
        float pv[16]; float sum = 0.f;
        #pragma unroll
        for (int kt = 0; kt < 4; kt++) {
            f32x4 bb = *(const f32x4*)(biasP + (((size_t)h * 16 + kt * 4 + qt) * 64 + lane) * 4);
            #pragma unroll
            for (int r = 0; r < 4; r++) {
                float p = __expf(st[kt][r] + bb[r]);
                p = (needmask && (rq[qt] != rk[kt][r])) ? 0.f : p;
                pv[kt * 4 + r] = p; sum += p;
            }
        }
        sum += __shfl_xor(sum, 16);
        sum += __shfl_xor(sum, 32);
        float rcp = 1.0f / sum;
        unsigned a0 = cvtpk(pv[0] * rcp, pv[1] * rcp);
        unsigned a1 = cvtpk(pv[2] * rcp, pv[3] * rcp);
        unsigned a2 = cvtpk(pv[4] * rcp, pv[5] * rcp);
        unsigned a3 = cvtpk(pv[6] * rcp, pv[7] * rcp);
        pa[qt][0] = regroup(a0, a1, a2, a3, lane);
        a0 = cvtpk(pv[8] * rcp,  pv[9] * rcp);
        a1 = cvtpk(pv[10] * rcp, pv[11] * rcp);
        a2 = cvtpk(pv[12] * rcp, pv[13] * rcp);
        a3 = cvtpk(pv[14] * rcp, pv[15] * rcp);
        pa[qt][1] = regroup(a0, a1, a2, a3, lane);
    }
    // V fragments from vT: A-op
    const short* vb = vT + ((size_t)w * HEADS + h) * 32 * 64;
    bf16x8 vfrag[2][2];
    #pragma unroll
    for (int ks2 = 0; ks2 < 2; ks2++)
        #pragma unroll
        for (int dt = 0; dt < 2; dt++)
            vfrag[ks2][dt] = __builtin_nontemporal_load(
                (const bf16x8*)(vb + (size_t)(dt * 16 + lrow) * 64 + ks2 * 32 + lhi * 8));
    // PV^T: ao2[qt][dt], col=query(lane&15), rows=4 consecutive dims
    f32x4 ao2[4][2];
    #pragma unroll
    for (int qt = 0; qt < 4; qt++) { ao2[qt][0] = zero; ao2[qt][1] = zero; }
    __builtin_amdgcn_s_setprio(1);
    #pragma unroll
    for (int ks2 = 0; ks2 < 2; ks2++)
        #pragma unroll
        for (int qt = 0; qt < 4; qt++) {
            ao2[qt][0] = __builtin_amdgcn_mfma_f32_16x16x32_bf16(vfrag[ks2][0], pa[qt][ks2], ao2[qt][0], 0, 0, 0);
            ao2[qt][1] = __builtin_amdgcn_mfma_f32_16x16x32_bf16(vfrag[ks2][1], pa[qt][ks2], ao2[qt][1], 0, 0, 0);
        }
    __builtin_amdgcn_s_setprio(0);
    // paired 8B NT stores (full 64B (token,head) line per 16-lane group)
    short* abase = attno + (size_t)(w * 64) * CDIM + h * 32 + lhi * 4;
    #pragma unroll
    for (int qt = 0; qt < 4; qt++) {
        int token = qt * 16 + lrow;
        short* p0 = abase + (size_t)token * CDIM;
        u32x2 s0, s1;
        s0[0] = cvtpk(ao2[qt][0][0], ao2[qt][0][1]);
        s0[1] = cvtpk(ao2[qt][0][2], ao2[qt][0][3]);
        s1[0] = cvtpk(ao2[qt][1][0], ao2[qt][1][1]);
        s1[1] = cvtpk(ao2[qt][1][2], ao2[qt][1][3]);
        __builtin_nontemporal_store(s0, (u32x2*)(p0));
        __builtin_nontemporal_store(s1, (u32x2*)(p0 + 16));
    }
}

// ---------------- GEMM2 (pipelined): out = attno @ proj_w^T + b ------------
__global__ __launch_bounds__(256) void gemm_proj(
    const short* __restrict__ a, const short* __restrict__ wt,
    const float* __restrict__ proj_b, float* __restrict__ out)
{
    __shared__ alignas(16) short As[8192];     // 2 buffers
    __shared__ alignas(16) short Bs[8192];
    int tid = threadIdx.x;
    int hw = blockIdx.x;                       // 3072 blocks, %8==0
    int lb = (hw & 7) * 384 + (hw >> 3);
    int bm = lb / 3, bn = lb - bm * 3;
    int m0 = bm * 128, n0 = bn * 128;

    int lane = tid & 63, wv = tid >> 6;
    int c0 = wv * 128 + lane, c1 = c0 + 64;
    int l0 = invswz(c0), l1 = invswz(c1);
    const short* Ag0 = a + (size_t)(m0 + (l0 >> 2)) * CDIM + (l0 & 3) * 8;
    const short* Ag1 = a + (size_t)(m0 + (l1 >> 2)) * CDIM + (l1 & 3) * 8;
    const short* Bg0 = wt + (size_t)(n0 + (l0 >> 2)) * CDIM + (l0 & 3) * 8;
    const short* Bg1 = wt + (size_t)(n0 + (l1 >> 2)) * CDIM + (l1 & 3) * 8;
    short* Adst0 = As + wv * 1024;
    short* Adst1 = Adst0 + 512;
    short* Bdst0 = Bs + wv * 1024;
    short* Bdst1 = Bdst0 + 512;

    int wr = wv >> 1, wc = wv & 1;
    int lrow = lane & 15, lhi = lane >> 4;
    int arow = wr * 64 + lrow, brow = wc * 64 + lrow;
    const short* ard = As + ((((arow * 64 + lhi * 16)) ^ ((lrow & 7) << 4)) >> 1);
    const short* brd = Bs + ((((brow * 64 + lhi * 16)) ^ ((lrow & 7) << 4)) >> 1);

    f32x4 zero = {0.f, 0.f, 0.f, 0.f};
    f32x4 acc[4][4];
    #pragma unroll
    for (int i = 0; i < 4; i++)
        #pragma unroll
        for (int j = 0; j < 4; j++) acc[i][j] = zero;

    gl16(Ag0, Adst0);
    gl16(Bg0, Bdst0);
    gl16(Ag1, Adst1);
    gl16(Bg1, Bdst1);
    __syncthreads();

    #pragma unroll
    for (int ks = 0; ks < 12; ks++) {
        int cur = (ks & 1) * 4096, nxt = 4096 - cur;
        if (ks < 11) {
            int k1 = (ks + 1) * 32;
            gl16(Ag0 + k1, Adst0 + nxt);
            gl16(Bg0 + k1, Bdst0 + nxt);
            gl16(Ag1 + k1, Adst1 + nxt);
            gl16(Bg1 + k1, Bdst1 + nxt);
        }
        bf16x8 af[4], bfr[4];
        #pragma unroll
        for (int t = 0; t < 4; t++) af[t]  = *(const bf16x8*)(ard + cur + t * 512);
        #pragma unroll
        for (int t = 0; t < 4; t++) bfr[t] = *(const bf16x8*)(brd + cur + t * 512);
        __builtin_amdgcn_s_setprio(1);
        #pragma unroll
        for (int i = 0; i < 4; i++)
            #pragma unroll
            for (int j = 0; j < 4; j++)
                acc[i][j] = __builtin_amdgcn_mfma_f32_16x16x32_bf16(af[i], bfr[j], acc[i][j], 0, 0, 0);
        __builtin_amdgcn_s_setprio(0);
        __syncthreads();
    }
    // epilogue: window reverse + unshift, fp32 NT out
    #pragma unroll
    for (int ti = 0; ti < 4; ti++) {
        #pragma unroll
        for (int r = 0; r < 4; r++) {
            int m = m0 + wr * 64 + ti * 16 + lhi * 4 + r;
            int b = m >> 12, wIdx = (m >> 6) & 63, tok = m & 63;
            int gh = ((wIdx >> 3) << 3) + (tok >> 3);
            int gw = (wIdx & 7) * 8 + (tok & 7);
            int ih = (gh + SHIFT_) & 63, iw = (gw + SHIFT_) & 63;
            size_t ob = ((size_t)(b << 12) + ih * 64 + iw) * CDIM;
            #pragma unroll
            for (int tj = 0; tj < 4; tj++) {
                int col = n0 + wc * 64 + tj * 16 + lrow;
                float v = acc[ti][tj][r] + proj_b[col];
                __builtin_nontemporal_store(v, &out[ob + col]);
            }
        }
    }
}

extern "C" void kernel_launch(void* const* d_in, const int* in_sizes, int n_in,
                              void* d_out, int out_size, void* d_ws, size_t ws_size,
                              hipStream_t stream) {
    const float* x          = (const float*)d_in[0];
    const float* qkv_w      = (const float*)d_in[1];
    const float* qkv_b      = (const float*)d_in[2];
    const float* proj_w     = (const float*)d_in[3];
    const float* proj_b     = (const float*)d_in[4];
    const float* bias_table = (const float*)d_in[5];
    const int*   rel_index  = (const int*)d_in[6];
    float* out = (float*)d_out;
    char* ws = (char*)d_ws;

    short* qkvwt = (short*)(ws);                    //    884736 B
    short* projwt = (short*)(ws + 884736);          //    294912 B
    float* biasP  = (float*)(ws + 1179648);         //    196608 B
    short* qkbuf  = (short*)(ws + 1376256);         // 201326592 B
    short* vT     = (short*)(ws + 202702848);       // 100663296 B
    short* attno  = (short*)(ws + 303366144);       // 100663296 B -> ~404 MB

    prep_kernel<<<1728, 256, 0, stream>>>(qkv_w, proj_w, bias_table, rel_index,
                                          qkvwt, projwt, biasP);
    gemm_qkv<<<9216, 256, 0, stream>>>(x, qkvwt, qkv_b, qkbuf, vT);
    attn_reg<<<6144, 256, 0, stream>>>(qkbuf, vT, biasP, attno);
    gemm_proj<<<3072, 256, 0, stream>>>(attno, projwt, proj_b, out);
}